// Round 5
// baseline (152.240 us; speedup 1.0000x reference)
//
#include <hip/hip_runtime.h>
#include <hip/hip_bf16.h>

typedef __attribute__((ext_vector_type(8))) short bf16x8;
typedef __attribute__((ext_vector_type(4))) float f32x4;
typedef float f32x4u __attribute__((ext_vector_type(4), aligned(4))); // 4B-aligned (LL=469 is odd)
typedef __attribute__((ext_vector_type(4))) short short4v;
typedef unsigned short ushort_t;

#define CC 120
#define LL 469
#define HH 64

constexpr int NBATCH = 1024;           // (s,b) pairs; raw reshape => batch contiguous
constexpr int KSTEPS = (LL + 31) / 32; // 15

// ---- LDS layout ----
// phase 1: Wl[2][192][40] bf16 @0 (30720 B). X never touches LDS (no reuse).
// phase 2: Qb @0 (16 KB, [128]x128B swz), Kb @16384, Vb @32768 ([64]x256B swz)
//          Pb @0 (32 KB) aliases Q+K after QK^T barrier
// epilogue: Ob f32 [120][68] @0
constexpr int WBUF_SHORTS = 192 * 40;            // 7680
constexpr int WBUF_BYTES  = WBUF_SHORTS * 2;     // 15360
constexpr int SMEM_BYTES  = 49152;               // phase2 needs 48K
constexpr int WIMG_BYTES  = KSTEPS * WBUF_BYTES; // 230400

__device__ __forceinline__ ushort_t f2bf(float f) {
  __hip_bfloat16 h = __float2bfloat16(f);
  return __builtin_bit_cast(ushort_t, h);
}

__device__ __forceinline__ void gload_lds16(const void* g, void* l) {
  __builtin_amdgcn_global_load_lds(
      (const __attribute__((address_space(1))) unsigned int*)g,
      (__attribute__((address_space(3))) unsigned int*)l, 16, 0, 0);
}

// XOR-swizzled LDS address for phase-2 tiles
__device__ __forceinline__ char* sptr(char* base, int row, int stride, int byteoff) {
  return base + row * stride + (byteoff ^ ((row & 7) << 4));
}

__global__ void prep_w(const float* __restrict__ Wk, const float* __restrict__ Wq,
                       const float* __restrict__ Wv, ushort_t* __restrict__ wimg) {
  int idx = blockIdx.x * 256 + threadIdx.x; // 15*192*40 = 115200 exactly
  int t = idx / (192 * 40);
  int rem = idx % (192 * 40);
  int col = rem / 40;
  int kk = rem % 40;
  int k = t * 32 + kk;
  int wsel = col >> 6, h = col & 63;
  const float* wp = (wsel == 0) ? Wk : (wsel == 1) ? Wq : Wv;
  float v = (kk < 32 && k < LL) ? wp[(size_t)k * HH + h] : 0.f;
  wimg[idx] = f2bf(v);
}

template <bool WIMG>
__global__ __launch_bounds__(256, 3)
void fused_regional_head(const float* __restrict__ x,
                         const float* __restrict__ Wk,
                         const float* __restrict__ Wq,
                         const float* __restrict__ Wv,
                         const ushort_t* __restrict__ wimg,
                         float* __restrict__ out) {
  __shared__ char smem[SMEM_BYTES];
  const int tid = threadIdx.x;
  const int lane = tid & 63;
  const int wv = tid >> 6;   // wave 0..3, owns rows 32*wv .. 32*wv+31
  const int lr = lane & 15;
  const int lg = lane >> 4;
  const int batch = blockIdx.x;
  const size_t xbase = (size_t)batch * CC * LL;

  ushort_t* Wl = (ushort_t*)smem; // [2][192][40] bf16

  const int row0 = wv * 32 + lr;      // < 120 always
  const int row1 = wv * 32 + 16 + lr; // >= 120 for wave3, lr>=8
  const bool r1ok = row1 < CC;
  const float* xr0 = x + xbase + (size_t)row0 * LL;
  const float* xr1 = x + xbase + (size_t)row1 * LL;

  // X A-fragment data, global -> registers. c[0..1]=row0 k+0..7, c[2..3]=row1.
  auto loadX = [&](int t, f32x4u* c) {
    const f32x4u z = (f32x4u){0.f, 0.f, 0.f, 0.f};
    if (t == KSTEPS - 1) { // tail: k = 448..468 guarded scalar loads
#pragma unroll
      for (int j = 0; j < 4; ++j) {
        int ka = 448 + lg * 8 + j, kb = ka + 4;
        c[0][j] = (ka < LL) ? xr0[ka] : 0.f;
        c[1][j] = (kb < LL) ? xr0[kb] : 0.f;
        c[2][j] = (r1ok && ka < LL) ? xr1[ka] : 0.f;
        c[3][j] = (r1ok && kb < LL) ? xr1[kb] : 0.f;
      }
    } else {
      const int off = t * 32 + lg * 8;
      c[0] = *(const f32x4u*)(xr0 + off);
      c[1] = *(const f32x4u*)(xr0 + off + 4);
      if (r1ok) {
        c[2] = *(const f32x4u*)(xr1 + off);
        c[3] = *(const f32x4u*)(xr1 + off + 4);
      } else { c[2] = z; c[3] = z; }
    }
  };

  auto stage_w = [&](int buf, int t) {
    ushort_t* wb = Wl + buf * WBUF_SHORTS;
    if constexpr (WIMG) {
      const char* src = (const char*)(wimg + t * WBUF_SHORTS);
#pragma unroll
      for (int i = 0; i < 4; ++i) {
        int c = wv + 4 * i; // 1024-byte chunks, 15 total
        if (c < 15) gload_lds16(src + c * 1024 + lane * 16, (char*)wb + c * 1024);
      }
    } else {
      const int k0 = t * 32;
#pragma unroll
      for (int j = 0; j < 24; ++j) {
        int idx = j * 256 + tid;
        int col = idx >> 5, kk = idx & 31;
        int k = k0 + kk;
        int wsel = col >> 6, h = col & 63;
        const float* wp = (wsel == 0) ? Wk : (wsel == 1) ? Wq : Wv;
        float v = (k < LL) ? wp[(size_t)k * HH + h] : 0.f;
        wb[col * 40 + kk] = f2bf(v);
      }
    }
  };

  // ---------------- phase 1: QKV = X @ [Wk|Wq|Wv] ----------------
  f32x4 acc[2][12];
#pragma unroll
  for (int m = 0; m < 2; ++m)
#pragma unroll
    for (int n = 0; n < 12; ++n) acc[m][n] = (f32x4){0.f, 0.f, 0.f, 0.f};

  f32x4u cx[4], nx[4];
  loadX(0, cx);
  stage_w(0, 0);
  __syncthreads(); // W(0) in LDS; cx drained

#pragma unroll
  for (int t = 0; t < KSTEPS; ++t) {
    // issue next step's loads first: full step of MFMA/ds_read cover
    if (t + 1 < KSTEPS) {
      loadX(t + 1, nx);
      stage_w((t + 1) & 1, t + 1);
    }
    bf16x8 a0, a1;
#pragma unroll
    for (int j = 0; j < 4; ++j) {
      a0[j] = (short)f2bf(cx[0][j]); a0[4 + j] = (short)f2bf(cx[1][j]);
      a1[j] = (short)f2bf(cx[2][j]); a1[4 + j] = (short)f2bf(cx[3][j]);
    }
    const ushort_t* wb = Wl + (t & 1) * WBUF_SHORTS;
#pragma unroll
    for (int n = 0; n < 12; ++n) {
      bf16x8 b = *(const bf16x8*)(wb + (n * 16 + lr) * 40 + lg * 8);
      acc[0][n] = __builtin_amdgcn_mfma_f32_16x16x32_bf16(a0, b, acc[0][n], 0, 0, 0);
      acc[1][n] = __builtin_amdgcn_mfma_f32_16x16x32_bf16(a1, b, acc[1][n], 0, 0, 0);
    }
    __syncthreads(); // W(t) reads done everywhere; W(t+1)+nx drained
#pragma unroll
    for (int j = 0; j < 4; ++j) cx[j] = nx[j];
  }

  // ---------------- write Q,K,V (bf16, swizzled) ----------------
  char* Qb = smem;
  char* Kb = smem + 16384;
  char* Vb = smem + 32768;
  char* Pb = smem;
#pragma unroll
  for (int mt = 0; mt < 2; ++mt) {
#pragma unroll
    for (int r = 0; r < 4; ++r) {
      int row = wv * 32 + mt * 16 + lg * 4 + r;
#pragma unroll
      for (int n = 0; n < 4; ++n) {
        *(ushort_t*)sptr(Kb, row, 128, (n * 16 + lr) * 2) = f2bf(acc[mt][n][r]);
        *(ushort_t*)sptr(Qb, row, 128, (n * 16 + lr) * 2) = f2bf(acc[mt][4 + n][r]);
      }
    }
    // V^T packed: 4 consecutive d-rows -> ds_write_b64
#pragma unroll
    for (int n = 0; n < 4; ++n) {
      short4v pk;
#pragma unroll
      for (int r = 0; r < 4; ++r) pk[r] = (short)f2bf(acc[mt][8 + n][r]);
      *(short4v*)sptr(Vb, n * 16 + lr, 256, (wv * 32 + mt * 16 + lg * 4) * 2) = pk;
    }
  }
  __syncthreads();

  // ---------------- QK^T ----------------
  f32x4 accw[2][8];
#pragma unroll
  for (int m = 0; m < 2; ++m)
#pragma unroll
    for (int n = 0; n < 8; ++n) accw[m][n] = (f32x4){0.f, 0.f, 0.f, 0.f};
#pragma unroll
  for (int ks = 0; ks < 2; ++ks) {
    bf16x8 a0 = *(const bf16x8*)sptr(Qb, wv * 32 + lr, 128, ks * 64 + lg * 16);
    bf16x8 a1 = *(const bf16x8*)sptr(Qb, wv * 32 + 16 + lr, 128, ks * 64 + lg * 16);
#pragma unroll
    for (int n = 0; n < 8; ++n) {
      bf16x8 b = *(const bf16x8*)sptr(Kb, n * 16 + lr, 128, ks * 64 + lg * 16);
      accw[0][n] = __builtin_amdgcn_mfma_f32_16x16x32_bf16(a0, b, accw[0][n], 0, 0, 0);
      accw[1][n] = __builtin_amdgcn_mfma_f32_16x16x32_bf16(a1, b, accw[1][n], 0, 0, 0);
    }
  }
  __syncthreads(); // all done reading Q/K before P overwrites

  // ---------------- softmax (wave-parallel over 16-lane col groups) ----------------
#pragma unroll
  for (int mt = 0; mt < 2; ++mt)
#pragma unroll
    for (int r = 0; r < 4; ++r) {
      float l[8];
      float m = -1e30f;
#pragma unroll
      for (int n = 0; n < 8; ++n) {
        float v = accw[mt][n][r] * 0.125f;
        if (n == 7 && lr >= 8) v = -1e30f; // col = 112+lr >= 120 masked
        l[n] = v;
        m = fmaxf(m, v);
      }
#pragma unroll
      for (int off = 1; off < 16; off <<= 1) m = fmaxf(m, __shfl_xor(m, off));
      float s = 0.f;
#pragma unroll
      for (int n = 0; n < 8; ++n) {
        float p = __expf(l[n] - m);
        l[n] = p;
        s += p;
      }
#pragma unroll
      for (int off = 1; off < 16; off <<= 1) s += __shfl_xor(s, off);
      float inv = 1.f / s;
      int row = wv * 32 + mt * 16 + lg * 4 + r;
#pragma unroll
      for (int n = 0; n < 8; ++n)
        *(ushort_t*)sptr(Pb, row, 256, (n * 16 + lr) * 2) = f2bf(l[n] * inv);
    }
  // no barrier: each wave reads only its own P rows; V covered by barrier above

  // ---------------- out = P @ V ----------------
  f32x4 acco[2][4];
#pragma unroll
  for (int m = 0; m < 2; ++m)
#pragma unroll
    for (int n = 0; n < 4; ++n) acco[m][n] = (f32x4){0.f, 0.f, 0.f, 0.f};
#pragma unroll
  for (int ks = 0; ks < 4; ++ks) {
    bf16x8 a0 = *(const bf16x8*)sptr(Pb, wv * 32 + lr, 256, ks * 64 + lg * 16);
    bf16x8 a1 = *(const bf16x8*)sptr(Pb, wv * 32 + 16 + lr, 256, ks * 64 + lg * 16);
#pragma unroll
    for (int n = 0; n < 4; ++n) {
      bf16x8 b = *(const bf16x8*)sptr(Vb, n * 16 + lr, 256, ks * 64 + lg * 16);
      acco[0][n] = __builtin_amdgcn_mfma_f32_16x16x32_bf16(a0, b, acco[0][n], 0, 0, 0);
      acco[1][n] = __builtin_amdgcn_mfma_f32_16x16x32_bf16(a1, b, acco[1][n], 0, 0, 0);
    }
  }

  // ---------------- epilogue: LDS transpose -> float4 coalesced stores ----------------
  __syncthreads(); // P/V dead
  float* Ob = (float*)smem; // [120][68] f32
#pragma unroll
  for (int mt = 0; mt < 2; ++mt)
#pragma unroll
    for (int r = 0; r < 4; ++r) {
      int row = wv * 32 + mt * 16 + lg * 4 + r;
      if (row < CC) {
#pragma unroll
        for (int n = 0; n < 4; ++n)
          Ob[row * 68 + n * 16 + lr] = acco[mt][n][r];
      }
    }
  __syncthreads();
  const size_t obase = (size_t)batch * CC * HH;
#pragma unroll
  for (int i = 0; i < 8; ++i) {
    int idx = i * 256 + tid; // float4 index, 1920 total
    if (idx < 1920) {
      int row = idx >> 4;
      int c4 = (idx & 15) * 4;
      f32x4 v = *(const f32x4*)(Ob + row * 68 + c4);
      *(f32x4*)(out + obase + (size_t)idx * 4) = v;
    }
  }
}

extern "C" void kernel_launch(void* const* d_in, const int* in_sizes, int n_in,
                              void* d_out, int out_size, void* d_ws, size_t ws_size,
                              hipStream_t stream) {
  (void)in_sizes; (void)n_in; (void)out_size;
  const float* x  = (const float*)d_in[0];
  const float* Wk = (const float*)d_in[1];
  const float* Wq = (const float*)d_in[2];
  const float* Wv = (const float*)d_in[3];
  float* out = (float*)d_out;
  if (ws_size >= (size_t)WIMG_BYTES && d_ws != nullptr) {
    ushort_t* wimg = (ushort_t*)d_ws;
    prep_w<<<450, 256, 0, stream>>>(Wk, Wq, Wv, wimg);
    fused_regional_head<true><<<NBATCH, 256, 0, stream>>>(x, Wk, Wq, Wv, wimg, out);
  } else {
    fused_regional_head<false><<<NBATCH, 256, 0, stream>>>(x, Wk, Wq, Wv, nullptr, out);
  }
}